// Round 10
// baseline (255.088 us; speedup 1.0000x reference)
//
#include <hip/hip_runtime.h>
#include <stdint.h>

#define N_ROWS 32768
#define K_CODES 8192
#define D_DIM 256
#define STEP_BYTES 33024   // 32 KiB bf16 codes + 256 B fp32 c2 table (16B-aligned)
#define NBUF 2

typedef __attribute__((ext_vector_type(8))) short short8;
typedef __attribute__((ext_vector_type(4))) float f32x4;

__device__ __forceinline__ unsigned short f2bf_rne(float f) {
  union { float f; unsigned u; } v; v.f = f;
  unsigned r = v.u + 0x7fffu + ((v.u >> 16) & 1u);
  return (unsigned short)(r >> 16);
}

// ---------------------------------------------------------------------------
// Prep: codebook fp32 -> bf16 (RNE), XOR-swizzled within each 512B row.
// Each 64-code step tile carries a 256 B fp32 |e|^2 table. Zeroes counts.
// ---------------------------------------------------------------------------
__global__ __launch_bounds__(256) void eprep_kernel(
    const float* __restrict__ cb, unsigned short* __restrict__ ehw,
    int* __restrict__ counts) {
  int w = threadIdx.x >> 6, lane = threadIdx.x & 63;
  int k = blockIdx.x * 4 + w;
  int gid = blockIdx.x * 256 + threadIdx.x;
  if (gid < K_CODES) counts[gid] = 0;
  const float4* src = (const float4*)(cb + (size_t)k * D_DIM);
  float4 v = src[lane];
  float vv[4] = {v.x, v.y, v.z, v.w};
  unsigned short h[4];
  float s = 0.f;
#pragma unroll
  for (int j = 0; j < 4; ++j) {
    float f = vv[j];
    s += f * f;
    h[j] = f2bf_rne(f);
  }
  char* stepb = (char*)ehw + (size_t)(k >> 6) * STEP_BYTES;
  int cl = k & 63;
  int off = (8 * lane) ^ ((k & 7) << 4);  // swizzle flips bits 4-6 only
  *(ushort4*)(stepb + cl * 512 + off) = make_ushort4(h[0], h[1], h[2], h[3]);
#pragma unroll
  for (int m = 1; m < 64; m <<= 1) s += __shfl_xor(s, m);
  if (lane == 0) *(float*)(stepb + 32768 + cl * 4) = s;  // fp32-exact |e|^2
}

// ---------------------------------------------------------------------------
// Argmin R10 — TLP: 2 blocks/CU. R8b (read halving) was null -> the residue
// over the 166 us/CU write-drain floor is single-pipeline serialization:
// one wave population alternating {vmcnt wait, barrier, compute, stage,
// store} idles the store port during wait/barrier/compute phases. Fix via
// occupancy, not reordering (R7 showed reordering hurts): NBUF=2, 256-thr
// blocks, 66 KiB LDS -> 2 co-resident blocks per CU; when one blocks on
// vmcnt/barrier the other issues stores. Inner loop byte-identical math.
//   512 blocks = 256 row-groups (128 rows) x 2 codebook halves (64 tiles).
//   4 waves x 32 rows; per tile 4 sequential 16-code subtiles.
//   zero-fill: block abid zeros enc chunk abid*2MiB; 32 KiB/iter (8 dwordx4
//   nt per wave, two-base for 13-bit imm); aligned full lines; head/tail
//   scalars in epilogue. ZST8P predication also guards chunk 511's OOB edge.
//   vmcnt stream: 9 loads + 8 stores per iter; wait vmcnt(8) uniform
//   (= Z_{t-1} younger than S_t); iter 0 peeled at vmcnt(0) (x-loads
//   uncounted). Store-ack deadline ~1.2 iters; TLP covers hiccups.
// ---------------------------------------------------------------------------
__global__ __launch_bounds__(256, 2) void argmin_kernel(
    const float* __restrict__ x, const unsigned short* __restrict__ ehw,
    float* __restrict__ dmh, int* __restrict__ mih,
    float* __restrict__ x2g, float* __restrict__ enc) {
  __shared__ __align__(16) char s_tiles[NBUF * STEP_BYTES];  // 64.5 KiB

  const int tid = threadIdx.x;
  const int abid = blockIdx.x;
  const int r = abid >> 1;            // row-group (0..255): rows r*128..+127
  const int h = abid & 1;             // codebook half: codes h*4096..+4095
  const int ww = tid >> 6;            // wave 0..3
  const int lane = tid & 63;
  const int l15 = lane & 15;
  const int kg = lane >> 4;
  const int row0c = r * 128;          // compute rows base

  auto STAGE = [&](int i, int b) {    // i = tile index within half (0..63)
    const char* g0 = (const char*)ehw + (size_t)(h * 64 + i) * STEP_BYTES
                     + ww * 8192 + lane * 16;
    char* l0 = s_tiles + b * STEP_BYTES + ww * 8192;  // wave-uniform base
#pragma unroll
    for (int j = 0; j < 8; ++j) {
      __builtin_amdgcn_global_load_lds(
          (const __attribute__((address_space(1))) unsigned int*)(g0 + j * 1024),
          (__attribute__((address_space(3))) unsigned int*)(l0 + j * 1024), 16, 0, 0);
    }
    // c2 table: 256 B; all 4 waves load redundantly (uniform 9 loads/stage)
    const char* g1 = (const char*)ehw + (size_t)(h * 64 + i) * STEP_BYTES
                     + 32768 + lane * 4;
    char* l1 = s_tiles + b * STEP_BYTES + 32768;
    __builtin_amdgcn_global_load_lds(
        (const __attribute__((address_space(1))) unsigned int*)g1,
        (__attribute__((address_space(3))) unsigned int*)l1, 4, 0, 0);
  };

  // zero-fill: chunk abid = 2 MiB at enc + abid*2MiB (== 8 mod 128).
  // 64 units of 32 KiB; wave ww covers 8 KiB/unit as 8 x dwordx4 nt
  // (two base regs: global_store imm offset is 13-bit signed).
  const f32x4 z4 = {0.f, 0.f, 0.f, 0.f};
  char* Sp = (char*)enc + (size_t)abid * 2097152;    // chunk start
  char* zb = Sp + 120 + ww * 8192 + lane * 16;       // aligned bulk base
  auto ZST8 = [&](const char* p) {
    const char* q = p + 4096;
    asm volatile(
        "global_store_dwordx4 %0, %2, off nt\n\t"
        "global_store_dwordx4 %0, %2, off offset:1024 nt\n\t"
        "global_store_dwordx4 %0, %2, off offset:2048 nt\n\t"
        "global_store_dwordx4 %0, %2, off offset:3072 nt\n\t"
        "global_store_dwordx4 %1, %2, off nt\n\t"
        "global_store_dwordx4 %1, %2, off offset:1024 nt\n\t"
        "global_store_dwordx4 %1, %2, off offset:2048 nt\n\t"
        "global_store_dwordx4 %1, %2, off offset:3072 nt"
        :: "v"(p), "v"(q), "v"(z4));
  };
  auto ZST8P = [&](const char* p) {   // unit 63 short 128 B: wave3 ln>=56 skip
    const char* q = p + 4096;
    asm volatile(
        "global_store_dwordx4 %0, %2, off nt\n\t"
        "global_store_dwordx4 %0, %2, off offset:1024 nt\n\t"
        "global_store_dwordx4 %0, %2, off offset:2048 nt\n\t"
        "global_store_dwordx4 %0, %2, off offset:3072 nt\n\t"
        "global_store_dwordx4 %1, %2, off nt\n\t"
        "global_store_dwordx4 %1, %2, off offset:1024 nt\n\t"
        "global_store_dwordx4 %1, %2, off offset:2048 nt"
        :: "v"(p), "v"(q), "v"(z4));
    if (ww < 3 || lane < 56) {
      asm volatile("global_store_dwordx4 %0, %1, off offset:3072 nt"
                   :: "v"(q), "v"(z4));
    }
  };

  // prologue: stage tile 0 only (depth-1 prefetch with NBUF=2)
  STAGE(0, 0);

  // A fragments: 32 rows/wave (2 subtiles of 16), bf16; |x|^2 to workspace.
  short8 a_h[2][8];
  float x2acc[2];
#pragma unroll
  for (int s = 0; s < 2; ++s) {
    const float* rp = x + (size_t)(row0c + ww * 32 + s * 16 + l15) * D_DIM + kg * 8;
    float s2 = 0.f;
#pragma unroll
    for (int ch = 0; ch < 8; ++ch) {
      const float4* p = (const float4*)(rp + ch * 32);
      float4 v0 = p[0], v1 = p[1];
      float f[8] = {v0.x, v0.y, v0.z, v0.w, v1.x, v1.y, v1.z, v1.w};
#pragma unroll
      for (int j = 0; j < 8; ++j) {
        s2 += f[j] * f[j];
        a_h[s][ch][j] = (short)f2bf_rne(f[j]);
      }
    }
    x2acc[s] = s2;
  }
#pragma unroll
  for (int s = 0; s < 2; ++s) {
    x2acc[s] += __shfl_xor(x2acc[s], 16);
    x2acc[s] += __shfl_xor(x2acc[s], 32);
  }
  if (lane < 16) {  // kg==0 lanes; both halves write identical values: benign
#pragma unroll
    for (int s = 0; s < 2; ++s)
      x2g[row0c + ww * 32 + s * 16 + l15] = x2acc[s];
  }

  float mn[8];
  int mi[8];
#pragma unroll
  for (int s = 0; s < 8; ++s) { mn[s] = 3.4e38f; mi[s] = 0x7fffffff; }

  const int xm = (l15 & 7) << 4;      // swizzle term: (code&7)<<4

  // COMPUTE: 4 sequential 16-code subtiles; vh/acc regs reused across cs.
  auto COMPUTE = [&](int t) {
    const char* bh = s_tiles + (t & 1) * STEP_BYTES;
#pragma unroll
    for (int cs = 0; cs < 4; ++cs) {
      const int c_l = cs * 16 + l15;          // code within the 64-code tile
      const int code = h * 4096 + t * 64 + c_l;
      const float c2 = *(const float*)(bh + 32768 + c_l * 4);
      const int rb = c_l * 512;
      short8 vh[8];
#pragma unroll
      for (int ch = 0; ch < 8; ++ch)
        vh[ch] = *(const short8*)(bh + rb + ((ch * 64 + kg * 16) ^ xm));
      f32x4 acc[2];
      acc[0] = (f32x4){0.f, 0.f, 0.f, 0.f};
      acc[1] = (f32x4){0.f, 0.f, 0.f, 0.f};
#pragma unroll
      for (int ch = 0; ch < 8; ++ch) {
        acc[0] = __builtin_amdgcn_mfma_f32_16x16x32_bf16(a_h[0][ch], vh[ch], acc[0], 0, 0, 0);
        acc[1] = __builtin_amdgcn_mfma_f32_16x16x32_bf16(a_h[1][ch], vh[ch], acc[1], 0, 0, 0);
      }
#pragma unroll
      for (int s = 0; s < 2; ++s) {
#pragma unroll
        for (int q = 0; q < 4; ++q) {
          float d = __builtin_fmaf(-2.f, acc[s][q], c2);   // |e|^2 - 2 x.e
          if (d < mn[s * 4 + q]) { mn[s * 4 + q] = d; mi[s * 4 + q] = code; }
        }
      }
    }
  };

  // iter 0 peeled: the x loads above are uncounted -> full drain for S_0.
  asm volatile("s_waitcnt vmcnt(0)" ::: "memory");
  __builtin_amdgcn_s_barrier();
  __builtin_amdgcn_sched_barrier(0);
  COMPUTE(0);
  STAGE(1, 1);
  ZST8(zb);
  // iters 1..62: wait for S_t; younger = Z_{t-1}(8) -> vmcnt(8).
  // STAGE(t+1) overwrites buf (t+1)&1, last read in COMPUTE(t-1): all waves
  // passed that before this barrier.
#pragma unroll 1
  for (int t = 1; t < 63; ++t) {
    asm volatile("s_waitcnt vmcnt(8)" ::: "memory");
    __builtin_amdgcn_s_barrier();
    __builtin_amdgcn_sched_barrier(0);
    COMPUTE(t);
    STAGE(t + 1, (t + 1) & 1);
    ZST8(zb + (size_t)t * 32768);
  }
  // t=63: no stage; final (short) unit 63.
  asm volatile("s_waitcnt vmcnt(8)" ::: "memory");
  __builtin_amdgcn_s_barrier();
  __builtin_amdgcn_sched_barrier(0);
  COMPUTE(63);
  ZST8P(zb + (size_t)63 * 32768);

  // head 120 B + tail 8 B of the chunk (mod-128 remainders)
  if (tid < 30) ((float*)Sp)[tid] = 0.f;
  if (tid < 2) *(float*)(Sp + 2097144 + 4 * tid) = 0.f;

  // reduce across the 16 lanes (l15) holding different codes of the same rows
#pragma unroll
  for (int m = 1; m < 16; m <<= 1) {
#pragma unroll
    for (int s = 0; s < 8; ++s) {
      float om = __shfl_xor(mn[s], m);
      int oi = __shfl_xor(mi[s], m);
      if (om < mn[s] || (om == mn[s] && oi < mi[s])) { mn[s] = om; mi[s] = oi; }
    }
  }
  // per-half result: row = row0c + ww*32 + s*16 + kg*4 + q  (l15==0 lanes)
  if (l15 == 0) {
    float* dmo = dmh + (size_t)h * N_ROWS;
    int* mio = mih + (size_t)h * N_ROWS;
#pragma unroll
    for (int s = 0; s < 2; ++s)
#pragma unroll
      for (int q = 0; q < 4; ++q) {
        int row = row0c + ww * 32 + s * 16 + kg * 4 + q;
        dmo[row] = mn[s * 4 + q];
        mio[row] = mi[s * 4 + q];
      }
  }
}

// ---------------------------------------------------------------------------
// Merge halves + epilogue: pick best of the two codebook halves per row
// (tie -> half 0, whose indices are smaller = reference argmin tiebreak),
// one-hot 1.0, histogram, SSE partials, quantized gather. Separate dispatch
// orders it after ALL argmin blocks' zero stores.
// ---------------------------------------------------------------------------
__global__ __launch_bounds__(256) void merge_kernel(
    const float* __restrict__ dmh, const int* __restrict__ mih,
    const float* __restrict__ x2g, const float* __restrict__ cb,
    float* __restrict__ quant, float* __restrict__ enc,
    int* __restrict__ counts, float* __restrict__ ssep) {
  __shared__ int s_bi[128];
  __shared__ float s_red[128];
  const int p = blockIdx.x;
  const int tid = threadIdx.x;
  if (tid < 128) {
    int row = p * 128 + tid;
    float d0 = dmh[row], d1 = dmh[N_ROWS + row];
    int i0 = mih[row], i1 = mih[N_ROWS + row];
    int best = (d1 < d0) ? i1 : i0;         // tie -> i0 (smaller index)
    float bm = (d1 < d0) ? d1 : d0;
    s_bi[tid] = best;
    s_red[tid] = bm + x2g[row];             // SSE(row) = dist + |x|^2
    enc[(size_t)row * K_CODES + best] = 1.0f;
    atomicAdd(&counts[best], 1);
  }
  __syncthreads();
  for (int m = 64; m > 0; m >>= 1) {
    if (tid < m) s_red[tid] += s_red[tid + m];
    __syncthreads();
  }
  if (tid == 0) ssep[p] = s_red[0];

  // quantized gather: 4 waves x 32 rows, coalesced scalar stores
  // (dest is 4B-aligned only: quant = out+1).
  const int ww = tid >> 6, lane = tid & 63;
  for (int rr = ww * 32; rr < ww * 32 + 32; ++rr) {
    int best = s_bi[rr];
    float4 v = ((const float4*)(cb + (size_t)best * D_DIM))[lane];
    float* qp = quant + (size_t)(p * 128 + rr) * D_DIM + lane * 4;
    qp[0] = v.x; qp[1] = v.y; qp[2] = v.z; qp[3] = v.w;
  }
}

// ---------------------------------------------------------------------------
// Finalize: vq_loss + perplexity (deterministic fixed-order reductions).
// ---------------------------------------------------------------------------
__global__ __launch_bounds__(256) void finalize_kernel(
    const float* __restrict__ ssep, const int* __restrict__ counts,
    float* __restrict__ out) {
  __shared__ float r1[256], r2[256];
  int t = threadIdx.x;
  float s1 = ssep[t];  // 256 merge blocks, one partial each
  float s2 = 0.f;
  for (int j = 0; j < 32; ++j) {
    float p = (float)counts[t * 32 + j] * (1.0f / 32768.f);
    s2 += p * logf(p + 1e-10f);
  }
  r1[t] = s1; r2[t] = s2;
  __syncthreads();
  for (int m = 128; m > 0; m >>= 1) {
    if (t < m) { r1[t] += r1[t + m]; r2[t] += r2[t + m]; }
    __syncthreads();
  }
  if (t == 0) {
    out[0] = 1.25f * r1[0] / 8388608.f;   // q_latent + 0.25*e_latent
    out[8388609] = expf(-r2[0]);          // perplexity
  }
}

extern "C" void kernel_launch(void* const* d_in, const int* in_sizes, int n_in,
                              void* d_out, int out_size, void* d_ws, size_t ws_size,
                              hipStream_t stream) {
  const float* x = (const float*)d_in[0];
  const float* cb = (const float*)d_in[1];
  float* out = (float*)d_out;
  char* w = (char*)d_ws;
  unsigned short* ehw = (unsigned short*)(w);           // 128*33024 = 4,227,072 B
  int* counts = (int*)(w + 4227072);                    // 32 KiB
  float* ssep = (float*)(w + 4259840);                  // 1 KiB (256 used)
  float* dmh = (float*)(w + 4260864);                   // [2][32768] f32 = 256 KiB
  int* mih = (int*)(w + 4523008);                       // [2][32768] i32 = 256 KiB
  float* x2g = (float*)(w + 4785152);                   // [32768] f32 = 128 KiB

  float* quant = out + 1;
  float* enc = out + 8388610;

  eprep_kernel<<<K_CODES / 4, 256, 0, stream>>>(cb, ehw, counts);
  argmin_kernel<<<512, 256, 0, stream>>>(x, ehw, dmh, mih, x2g, enc);
  merge_kernel<<<256, 256, 0, stream>>>(dmh, mih, x2g, cb, quant, enc, counts, ssep);
  finalize_kernel<<<1, 256, 0, stream>>>(ssep, counts, out);
}

// Round 11
// 249.872 us; speedup vs baseline: 1.0209x; 1.0209x over previous
//
#include <hip/hip_runtime.h>
#include <stdint.h>

#define N_ROWS 32768
#define K_CODES 8192
#define D_DIM 256
#define STEP_BYTES 33024   // 32 KiB bf16 codes + 256 B fp32 c2 table (16B-aligned)
#define NBUF 4

typedef __attribute__((ext_vector_type(8))) short short8;
typedef __attribute__((ext_vector_type(4))) float f32x4;

__device__ __forceinline__ unsigned short f2bf_rne(float f) {
  union { float f; unsigned u; } v; v.f = f;
  unsigned r = v.u + 0x7fffu + ((v.u >> 16) & 1u);
  return (unsigned short)(r >> 16);
}

// ---------------------------------------------------------------------------
// Prep: codebook fp32 -> bf16 (RNE), XOR-swizzled within each 512B row.
// Each 64-code step tile carries a 256 B fp32 |e|^2 table. Zeroes counts.
// (unchanged)
// ---------------------------------------------------------------------------
__global__ __launch_bounds__(256) void eprep_kernel(
    const float* __restrict__ cb, unsigned short* __restrict__ ehw,
    int* __restrict__ counts) {
  int w = threadIdx.x >> 6, lane = threadIdx.x & 63;
  int k = blockIdx.x * 4 + w;
  int gid = blockIdx.x * 256 + threadIdx.x;
  if (gid < K_CODES) counts[gid] = 0;
  const float4* src = (const float4*)(cb + (size_t)k * D_DIM);
  float4 v = src[lane];
  float vv[4] = {v.x, v.y, v.z, v.w};
  unsigned short h[4];
  float s = 0.f;
#pragma unroll
  for (int j = 0; j < 4; ++j) {
    float f = vv[j];
    s += f * f;
    h[j] = f2bf_rne(f);
  }
  char* stepb = (char*)ehw + (size_t)(k >> 6) * STEP_BYTES;
  int cl = k & 63;
  int off = (8 * lane) ^ ((k & 7) << 4);  // swizzle flips bits 4-6 only
  *(ushort4*)(stepb + cl * 512 + off) = make_ushort4(h[0], h[1], h[2], h[3]);
#pragma unroll
  for (int m = 1; m < 64; m <<= 1) s += __shfl_xor(s, m);
  if (lane == 0) *(float*)(stepb + 32768 + cl * 4) = s;  // fp32-exact |e|^2
}

// ---------------------------------------------------------------------------
// Argmin R11 — BARRIER-FREE wave-private pipeline. Every prior round kept
// block-wide {vmcnt wait; s_barrier} lockstep because waves shared staged
// tiles; R8b proved bandwidth is NOT binding (read-halving null), so the
// residue over the write-drain floor is the lockstep itself. Now:
//   - 4 waves/block; wave cg owns codes cg*16..+15 of every 64-code tile and
//     stages its PRIVATE 8 KiB slice + private 256 B c2 copy. It reads only
//     what it staged -> correctness from its OWN vmcnt. NO barriers in loop.
//   - To keep per-CU read traffic identical to R5 (no duplication), each
//     wave computes ALL 128 rows: a_h[8][8] = 256 VGPRs of A-fragments
//     (total ~410, 1 wave/SIMD, __launch_bounds__(256,1); no spill <=450).
//   - Waves free-run; store port fed by 4 independent self-paced streams.
//   - vmcnt stream/wave: STAGE = 9 loads (8 wide + c2), ZST8 = 8 stores.
//     Loop: [wait vmcnt(42)] COMPUTE(t); STAGE(t+3); ZST8(t+3).
//     Tails 42/25/8. Prologue: A-loads (self-draining) then S0..Z2.
//   - One __syncthreads after the K loop; R5's single-kernel epilogue.
// ---------------------------------------------------------------------------
__global__ __launch_bounds__(256, 1) void argmin_kernel(
    const float* __restrict__ x, const float* __restrict__ cb,
    const unsigned short* __restrict__ ehw,
    float* __restrict__ quant, int* __restrict__ counts,
    float* __restrict__ ssep, float* __restrict__ enc) {
  __shared__ __align__(16) char s_tiles[NBUF * 32768];   // 128 KiB, wave-sliced
  __shared__ float s_c2[NBUF][4][64];                    // 4 KiB private c2
  __shared__ float s_x2[128];
  __shared__ float s_red[128];
  // epilogue-only arrays aliased onto s_tiles (dead after the K loop):
  float (*s_mn)[128] = (float (*)[128])(s_tiles);        // 2 KiB
  int (*s_mi)[128] = (int (*)[128])(s_tiles + 2048);     // 2 KiB

  const int tid = threadIdx.x;
  const int abid = blockIdx.x;
  const int cg = tid >> 6;            // wave id == code group (0..3)
  const int lane = tid & 63;
  const int l15 = lane & 15;
  const int kg = lane >> 4;
  const int row0 = abid * 128;

  // STAGE: wave-private slice (codes cg*16..+15 = 8 KiB contiguous) + c2.
  auto STAGE = [&](int i, int b) {
    const char* g0 = (const char*)ehw + (size_t)i * STEP_BYTES
                     + cg * 8192 + lane * 16;
    char* l0 = s_tiles + b * 32768 + cg * 8192;   // wave-uniform base
#pragma unroll
    for (int j = 0; j < 8; ++j) {
      __builtin_amdgcn_global_load_lds(
          (const __attribute__((address_space(1))) unsigned int*)(g0 + j * 1024),
          (__attribute__((address_space(3))) unsigned int*)(l0 + j * 1024), 16, 0, 0);
    }
    const char* g1 = (const char*)ehw + (size_t)i * STEP_BYTES + 32768 + lane * 4;
    char* l1 = (char*)&s_c2[b][cg][0];
    __builtin_amdgcn_global_load_lds(
        (const __attribute__((address_space(1))) unsigned int*)g1,
        (__attribute__((address_space(3))) unsigned int*)l1, 4, 0, 0);
  };

  // zero-fill: unit u = 32 KiB at Sp+120 + u*32768; wave cg covers 8 KiB as
  // 8 x dwordx4 nt (full lines; two base regs: imm offset is 13-bit signed).
  const f32x4 z4 = {0.f, 0.f, 0.f, 0.f};
  char* Sp = (char*)enc + (size_t)row0 * 32768;      // block region start
  char* zb = Sp + 120 + cg * 8192 + lane * 16;       // aligned bulk base
  auto ZST8 = [&](const char* p) {
    const char* q = p + 4096;
    asm volatile(
        "global_store_dwordx4 %0, %2, off nt\n\t"
        "global_store_dwordx4 %0, %2, off offset:1024 nt\n\t"
        "global_store_dwordx4 %0, %2, off offset:2048 nt\n\t"
        "global_store_dwordx4 %0, %2, off offset:3072 nt\n\t"
        "global_store_dwordx4 %1, %2, off nt\n\t"
        "global_store_dwordx4 %1, %2, off offset:1024 nt\n\t"
        "global_store_dwordx4 %1, %2, off offset:2048 nt\n\t"
        "global_store_dwordx4 %1, %2, off offset:3072 nt"
        :: "v"(p), "v"(q), "v"(z4));
  };
  auto ZST8P = [&](const char* p) {   // unit 127 short 128 B: cg3 ln>=56 skip
    const char* q = p + 4096;
    asm volatile(
        "global_store_dwordx4 %0, %2, off nt\n\t"
        "global_store_dwordx4 %0, %2, off offset:1024 nt\n\t"
        "global_store_dwordx4 %0, %2, off offset:2048 nt\n\t"
        "global_store_dwordx4 %0, %2, off offset:3072 nt\n\t"
        "global_store_dwordx4 %1, %2, off nt\n\t"
        "global_store_dwordx4 %1, %2, off offset:1024 nt\n\t"
        "global_store_dwordx4 %1, %2, off offset:2048 nt"
        :: "v"(p), "v"(q), "v"(z4));
    if (cg < 3 || lane < 56) {
      asm volatile("global_store_dwordx4 %0, %1, off offset:3072 nt"
                   :: "v"(q), "v"(z4));
    }
  };

  // A fragments FIRST (their loads drain via the f2bf consumption below, so
  // the K-loop vmcnt stream starts clean): all 128 rows per wave, 8 subtiles.
  short8 a_h[8][8];
  float x2acc[8];
#pragma unroll
  for (int s = 0; s < 8; ++s) {
    const float* rp = x + (size_t)(row0 + s * 16 + l15) * D_DIM + kg * 8;
    float s2 = 0.f;
#pragma unroll
    for (int ch = 0; ch < 8; ++ch) {
      const float4* p = (const float4*)(rp + ch * 32);
      float4 v0 = p[0], v1 = p[1];
      float f[8] = {v0.x, v0.y, v0.z, v0.w, v1.x, v1.y, v1.z, v1.w};
#pragma unroll
      for (int j = 0; j < 8; ++j) {
        s2 += f[j] * f[j];
        a_h[s][ch][j] = (short)f2bf_rne(f[j]);
      }
    }
    x2acc[s] = s2;
  }
#pragma unroll
  for (int s = 0; s < 8; ++s) {
    x2acc[s] += __shfl_xor(x2acc[s], 16);
    x2acc[s] += __shfl_xor(x2acc[s], 32);
  }
  if (cg == 0 && lane < 16) {
#pragma unroll
    for (int s = 0; s < 8; ++s) s_x2[s * 16 + l15] = x2acc[s];
  }

  // prologue: S0 Z0 S1 Z1 S2 Z2 — 51 outstanding; wait 42 completes S0.
  STAGE(0, 0); ZST8(zb);
  STAGE(1, 1); ZST8(zb + 32768);
  STAGE(2, 2); ZST8(zb + 2 * 32768);

  float mn[32];
  int mi[32];
#pragma unroll
  for (int s = 0; s < 32; ++s) { mn[s] = 3.4e38f; mi[s] = 0x7fffffff; }

  const int xm = (l15 & 7) << 4;      // swizzle term: (code&7)<<4

  // COMPUTE: wave-private slice; 8 vh ds_read_b128 + c2; 64 MFMA (8 subtiles
  // x 8 ch, ch-outer for ILP-8 across acc chains); min-update for 128 rows.
  auto COMPUTE = [&](int t) {
    const char* bh = s_tiles + (t & 3) * 32768 + cg * 8192;
    const int code = t * 64 + cg * 16 + l15;
    const float c2 = s_c2[t & 3][cg][cg * 16 + l15];
    short8 vh[8];
#pragma unroll
    for (int ch = 0; ch < 8; ++ch)
      vh[ch] = *(const short8*)(bh + l15 * 512 + ((ch * 64 + kg * 16) ^ xm));
    f32x4 acc[8];
#pragma unroll
    for (int s = 0; s < 8; ++s) acc[s] = (f32x4){0.f, 0.f, 0.f, 0.f};
#pragma unroll
    for (int ch = 0; ch < 8; ++ch) {
#pragma unroll
      for (int s = 0; s < 8; ++s)
        acc[s] = __builtin_amdgcn_mfma_f32_16x16x32_bf16(a_h[s][ch], vh[ch], acc[s], 0, 0, 0);
    }
#pragma unroll
    for (int s = 0; s < 8; ++s) {
#pragma unroll
      for (int q = 0; q < 4; ++q) {
        float d = __builtin_fmaf(-2.f, acc[s][q], c2);   // |e|^2 - 2 x.e
        if (d < mn[s * 4 + q]) { mn[s * 4 + q] = d; mi[s * 4 + q] = code; }
      }
    }
  };

  // K loop, NO barriers: wave self-paces on its own vmcnt.
  // wait for S_t: younger = Z_t(8) + (S+Z)x2 (17x2) = 42.
  // LDS safety: STAGE(t+3) overwrites this wave's own slice of buf (t-1)&3,
  // fully consumed by this wave's COMPUTE(t-1) (program order).
#pragma unroll 1
  for (int t = 0; t < 125; ++t) {
    asm volatile("s_waitcnt vmcnt(42)" ::: "memory");
    __builtin_amdgcn_sched_barrier(0);
    COMPUTE(t);
    if (t < 124) {
      STAGE(t + 3, (t + 3) & 3);
      ZST8(zb + (size_t)(t + 3) * 32768);
    } else {
      STAGE(127, 127 & 3);
      ZST8P(zb + (size_t)127 * 32768);
    }
  }
  // t=125: younger than S_125 = Z125(8)+S126(9)+Z126(8)+S127(9)+Z127(8)=42.
  asm volatile("s_waitcnt vmcnt(42)" ::: "memory");
  __builtin_amdgcn_sched_barrier(0);
  COMPUTE(125);
  // t=126: younger than S_126 = Z126(8)+S127(9)+Z127(8) = 25.
  asm volatile("s_waitcnt vmcnt(25)" ::: "memory");
  __builtin_amdgcn_sched_barrier(0);
  COMPUTE(126);
  // t=127: younger than S_127 = Z127(8).
  asm volatile("s_waitcnt vmcnt(8)" ::: "memory");
  __builtin_amdgcn_sched_barrier(0);
  COMPUTE(127);

  // head 120 B + tail 8 B of the block's enc region (mod-128 remainders)
  if (tid < 30) ((float*)Sp)[tid] = 0.f;
  if (tid < 2) *(float*)(Sp + 4194296 + 4 * tid) = 0.f;

  // reduce across the 16 lanes (l15) holding different codes of the same rows
#pragma unroll
  for (int m = 1; m < 16; m <<= 1) {
#pragma unroll
    for (int s = 0; s < 32; ++s) {
      float om = __shfl_xor(mn[s], m);
      int oi = __shfl_xor(mi[s], m);
      if (om < mn[s] || (om == mn[s] && oi < mi[s])) { mn[s] = om; mi[s] = oi; }
    }
  }
  // per-wave result covers ALL 128 rows: row = s*16 + kg*4 + q (l15==0)
  if (l15 == 0) {
#pragma unroll
    for (int s = 0; s < 8; ++s)
#pragma unroll
      for (int q = 0; q < 4; ++q)
        { int lr = s * 16 + kg * 4 + q;
          s_mn[cg][lr] = mn[s * 4 + q]; s_mi[cg][lr] = mi[s * 4 + q]; }
  }
  // drain this wave's zero stores; barrier => all waves' zeros ordered at L2
  // before any 1.0 one-hot store below.
  asm volatile("s_waitcnt vmcnt(0)" ::: "memory");
  __syncthreads();

  // merge 4 code-groups; one-hot 1.0 scatter; histogram; SSE partial
  if (tid < 128) {
    float bm = s_mn[0][tid]; int best = s_mi[0][tid];
#pragma unroll
    for (int c = 1; c < 4; ++c) {
      float m2 = s_mn[c][tid]; int i2 = s_mi[c][tid];
      if (m2 < bm || (m2 == bm && i2 < best)) { bm = m2; best = i2; }
    }
    s_mi[0][tid] = best;                       // publish for gather below
    s_red[tid] = bm + s_x2[tid];               // SSE(row) = dist + |x|^2
    enc[(size_t)(row0 + tid) * K_CODES + best] = 1.0f;
    atomicAdd(&counts[best], 1);
  }
  __syncthreads();
  for (int m = 64; m > 0; m >>= 1) {
    if (tid < m) s_red[tid] += s_red[tid + m];
    __syncthreads();
  }
  if (tid == 0) ssep[abid] = s_red[0];

  // quantized gather: 4 waves x 32 rows, coalesced plain scalar stores
  // (dest is 4B-aligned only: quant = out+1).
  for (int r = cg * 32; r < cg * 32 + 32; ++r) {
    int best = s_mi[0][r];
    float4 v = ((const float4*)(cb + (size_t)best * D_DIM))[lane];
    float* qp = quant + (size_t)(row0 + r) * D_DIM + lane * 4;
    qp[0] = v.x; qp[1] = v.y; qp[2] = v.z; qp[3] = v.w;
  }
}

// ---------------------------------------------------------------------------
// Finalize: vq_loss + perplexity (deterministic fixed-order reductions).
// ---------------------------------------------------------------------------
__global__ __launch_bounds__(256) void finalize_kernel(
    const float* __restrict__ ssep, const int* __restrict__ counts,
    float* __restrict__ out) {
  __shared__ float r1[256], r2[256];
  int t = threadIdx.x;
  float s1 = ssep[t];  // 256 argmin blocks, one partial each
  float s2 = 0.f;
  for (int j = 0; j < 32; ++j) {
    float p = (float)counts[t * 32 + j] * (1.0f / 32768.f);
    s2 += p * logf(p + 1e-10f);
  }
  r1[t] = s1; r2[t] = s2;
  __syncthreads();
  for (int m = 128; m > 0; m >>= 1) {
    if (t < m) { r1[t] += r1[t + m]; r2[t] += r2[t + m]; }
    __syncthreads();
  }
  if (t == 0) {
    out[0] = 1.25f * r1[0] / 8388608.f;   // q_latent + 0.25*e_latent
    out[8388609] = expf(-r2[0]);          // perplexity
  }
}

extern "C" void kernel_launch(void* const* d_in, const int* in_sizes, int n_in,
                              void* d_out, int out_size, void* d_ws, size_t ws_size,
                              hipStream_t stream) {
  const float* x = (const float*)d_in[0];
  const float* cb = (const float*)d_in[1];
  float* out = (float*)d_out;
  char* w = (char*)d_ws;
  unsigned short* ehw = (unsigned short*)(w);           // 128*33024 = 4,227,072 B
  int* counts = (int*)(w + 4227072);                    // 32 KiB
  float* ssep = (float*)(w + 4259840);                  // 1 KiB

  float* quant = out + 1;
  float* enc = out + 8388610;

  eprep_kernel<<<K_CODES / 4, 256, 0, stream>>>(cb, ehw, counts);
  argmin_kernel<<<256, 256, 0, stream>>>(x, cb, ehw, quant, counts, ssep, enc);
  finalize_kernel<<<1, 256, 0, stream>>>(ssep, counts, out);
}